// Round 5
// baseline (24.855 us; speedup 1.0000x reference)
//
#include <hip/hip_runtime.h>

#define POLY_N   16777216
#define POLY_DIM 16
#define N4       (POLY_N / 4)        // 4194304 float4 elements
#define BLOCK    256
#define PER_THR  2                   // two float4s per thread, block-contiguous
#define GRID     (N4 / (BLOCK * PER_THR))   // 8192 blocks

typedef float f32x4 __attribute__((ext_vector_type(4)));

__global__ __launch_bounds__(BLOCK) void poly_horner_kernel(
        const float* __restrict__ x,
        const float* __restrict__ w,
        float* __restrict__ out) {
    const f32x4* __restrict__ x4 = reinterpret_cast<const f32x4*>(x);
    f32x4* __restrict__       o4 = reinterpret_cast<f32x4*>(out);

    const int base = blockIdx.x * (BLOCK * PER_THR) + threadIdx.x;

    // Two independent loads in flight, addresses adjacent at block scope
    // (4 KB apart per lane-pair) -> DRAM page locality preserved.
    f32x4 v0 = x4[base];
    f32x4 v1 = x4[base + BLOCK];

    float c[POLY_DIM];
#pragma unroll
    for (int i = 0; i < POLY_DIM; ++i) c[i] = w[i];

    f32x4 r0, r1;
#define HORNER(dst, src)                                                  \
    {                                                                     \
        float a = c[POLY_DIM - 1];                                        \
        _Pragma("unroll")                                                 \
        for (int j = POLY_DIM - 2; j >= 0; --j) a = fmaf(a, (src), c[j]); \
        (dst) = a;                                                        \
    }
    HORNER(r0.x, v0.x) HORNER(r0.y, v0.y) HORNER(r0.z, v0.z) HORNER(r0.w, v0.w)
    HORNER(r1.x, v1.x) HORNER(r1.y, v1.y) HORNER(r1.z, v1.z) HORNER(r1.w, v1.w)
#undef HORNER

    o4[base]         = r0;
    o4[base + BLOCK] = r1;
}

extern "C" void kernel_launch(void* const* d_in, const int* in_sizes, int n_in,
                              void* d_out, int out_size, void* d_ws, size_t ws_size,
                              hipStream_t stream) {
    const float* x = (const float*)d_in[0];
    const float* w = (const float*)d_in[1];
    float* out     = (float*)d_out;

    poly_horner_kernel<<<GRID, BLOCK, 0, stream>>>(x, w, out);
}

// Round 7
// 24.392 us; speedup vs baseline: 1.0190x; 1.0190x over previous
//
#include <hip/hip_runtime.h>

#define POLY_N   16777216
#define POLY_DIM 16
#define N4       (POLY_N / 4)      // 4194304 float4 elements
#define BLOCK    256
#define GRID     (N4 / BLOCK)      // 16384 blocks, exactly one float4 per thread

typedef float f32x4 __attribute__((ext_vector_type(4)));

__global__ __launch_bounds__(BLOCK) void poly_horner_kernel(
        const float* __restrict__ x,
        const float* __restrict__ w,
        float* __restrict__ out) {
    const f32x4* __restrict__ x4 = reinterpret_cast<const f32x4*>(x);
    f32x4* __restrict__       o4 = reinterpret_cast<f32x4*>(out);

    const int tid = blockIdx.x * BLOCK + threadIdx.x;

    // Data load first so it's in flight during the scalar coefficient loads.
    f32x4 v = x4[tid];

    float c[POLY_DIM];
#pragma unroll
    for (int i = 0; i < POLY_DIM; ++i) c[i] = w[i];

    f32x4 r;
#define HORNER(dst, src)                                                  \
    {                                                                     \
        float a = c[POLY_DIM - 1];                                        \
        _Pragma("unroll")                                                 \
        for (int j = POLY_DIM - 2; j >= 0; --j) a = fmaf(a, (src), c[j]); \
        (dst) = a;                                                        \
    }
    HORNER(r.x, v.x)
    HORNER(r.y, v.y)
    HORNER(r.z, v.z)
    HORNER(r.w, v.w)
#undef HORNER

    o4[tid] = r;   // plain store: NT stores break post-timing validation (R6)
}

extern "C" void kernel_launch(void* const* d_in, const int* in_sizes, int n_in,
                              void* d_out, int out_size, void* d_ws, size_t ws_size,
                              hipStream_t stream) {
    const float* x = (const float*)d_in[0];
    const float* w = (const float*)d_in[1];
    float* out     = (float*)d_out;

    poly_horner_kernel<<<GRID, BLOCK, 0, stream>>>(x, w, out);
}